// Round 8
// baseline (47.412 us; speedup 1.0000x reference)
//
#include <hip/hip_runtime.h>
#include <hip/hip_bf16.h>
#include <hip/hip_fp16.h>

#define NN 1024   // nodes
#define FD 64     // feature dim (in == out)
#define BB 32     // batch

typedef __attribute__((ext_vector_type(4))) float    f32x4;
typedef __attribute__((ext_vector_type(8))) _Float16 f16x8;

static __device__ __forceinline__ unsigned short f2hu(float x) {
  _Float16 h = (_Float16)x;
  return __builtin_bit_cast(unsigned short, h);
}

// ---------------- Kernel 01 (fused):
//  blocks 0..511    : k1 (validated): h = x@W fp32, f, g, hT fp16 o-major
//  blocks 512..2559 : adj -> 64-bit row-tile masks via __ballot (pure streamer)
__global__ __launch_bounds__(256) void gat_k01(
    const float* __restrict__ x, const float* __restrict__ W,
    const float* __restrict__ av, const int* __restrict__ adj,
    float* __restrict__ fv, float* __restrict__ gv,
    unsigned short* __restrict__ hT, unsigned long long* __restrict__ maskG)
{
  __shared__ __align__(16) float Wl[FD * FD];          // 16 KB
  __shared__ __align__(16) float xl[FD * 68];          // 17 KB
  __shared__ __align__(16) unsigned short tl[FD * FD]; // 8 KB
  __shared__ __align__(16) float al[2 * FD];           // 0.5 KB

  const int tid = threadIdx.x;
  const int id  = blockIdx.x;

  if (id < 512) {
    // ================= k1 branch (verbatim from validated R7) =================
    const int b   = id >> 4;
    const int n0  = (id & 15) << 6;

    if (tid < 32) ((f32x4*)al)[tid] = ((const f32x4*)av)[tid];
    {
      const int r  = tid >> 2;
      const int cb = (tid & 3) << 2;
      const f32x4* Wg = (const f32x4*)W;
      const f32x4* xg = (const f32x4*)(x + ((size_t)(b * NN + n0)) * FD);
#pragma unroll
      for (int k = 0; k < 4; ++k) {
        f32x4 wv = Wg[r * 16 + cb + k];
        f32x4 xv = xg[r * 16 + cb + k];
        *(f32x4*)(Wl + r * FD + ((cb + k) << 2)) = wv;
        *(f32x4*)(xl + r * 68 + ((cb + k) << 2)) = xv;
      }
    }
    __syncthreads();

    const int r  = tid >> 2;
    const int o0 = (tid & 3) << 4;
    float acc[16];
#pragma unroll
    for (int i = 0; i < 16; ++i) acc[i] = 0.f;

#pragma unroll 8
    for (int f = 0; f < FD; ++f) {
      float xv = xl[r * 68 + f];
      const f32x4* wr = (const f32x4*)(Wl + f * FD + o0);
#pragma unroll
      for (int c = 0; c < 4; ++c) {
        f32x4 wv = wr[c];
        acc[c * 4 + 0] += xv * wv.x;
        acc[c * 4 + 1] += xv * wv.y;
        acc[c * 4 + 2] += xv * wv.z;
        acc[c * 4 + 3] += xv * wv.w;
      }
    }

    float fp = 0.f, gp = 0.f;
#pragma unroll
    for (int i = 0; i < 16; ++i) {
      fp += acc[i] * al[o0 + i];
      gp += acc[i] * al[FD + o0 + i];
    }
    fp += __shfl_xor(fp, 1); fp += __shfl_xor(fp, 2);
    gp += __shfl_xor(gp, 1); gp += __shfl_xor(gp, 2);
    if ((tid & 3) == 0) {
      fv[b * NN + n0 + r] = fp;
      gv[b * NN + n0 + r] = gp;
    }

#pragma unroll
    for (int i = 0; i < 16; ++i) {
      int o  = o0 + i;
      int sw = (o ^ (o >> 3)) & 7;
      tl[o * FD + ((((r >> 3) ^ sw) << 3) | (r & 7))] = f2hu(acc[i]);
    }
    __syncthreads();
    {
      const int c2 = tid & 7;
#pragma unroll
      for (int hh = 0; hh < 2; ++hh) {
        int o  = (tid >> 3) + 32 * hh;
        int sw = (o ^ (o >> 3)) & 7;
        f32x4 v = *(const f32x4*)(tl + o * FD + ((c2 ^ sw) << 3));
        *(f32x4*)(hT + ((size_t)(b * FD + o)) * NN + n0 + c2 * 8) = v;
      }
    }
  } else {
    // ================= ballot-compress branch =================
    // wave gw handles 4 rows; per row: 16 coalesced 256B loads + 16 ballots,
    // lanes 0..15 store the row's 16 u64 masks (128B contiguous).
    const int cid = id - 512;               // 0..2047
    const int w = tid >> 6, l = tid & 63;
    const int gw = cid * 4 + w;             // 0..8191
#pragma unroll
    for (int rr = 0; rr < 4; ++rr) {
      const int rowid = gw * 4 + rr;        // 0..32767 == b*1024 + i
      const int* rp = adj + ((size_t)rowid << 10);
      unsigned long long keep = 0ull;
#pragma unroll
      for (int t = 0; t < 16; ++t) {
        unsigned long long bl = __ballot(rp[t * 64 + l] > 0);
        if (l == t) keep = bl;              // lane t keeps tile t's mask
      }
      if (l < 16) maskG[((size_t)rowid << 4) + l] = keep;
    }
  }
}

// ---------------- Kernel 2: fused masked-softmax attention + PV (MFMA) + elu
// R7 skeleton (validated): 1024 blocks, 32-row i-tiles, double-buffered
// Pl/Hl, raw s_barrier (no vmcnt drain), distance-2 register prefetch,
// staggered j-order. adj int4 loads replaced by one u64 mask per row-tile.
__global__ __launch_bounds__(256) void gat_k2(
    const unsigned long long* __restrict__ maskG, const float* __restrict__ fv,
    const float* __restrict__ gv, const unsigned short* __restrict__ hT,
    float* __restrict__ out)
{
  __shared__ __align__(16) unsigned short Pl[2][32 * 64]; // 2 x 4 KB
  __shared__ __align__(16) unsigned short Hl[2][64 * 64]; // 2 x 8 KB
  __shared__ __align__(16) float gl[NN];                  // 4 KB
  __shared__ float dLds[32];
  __shared__ float red[8];

  const int tid  = threadIdx.x;
  const int b    = blockIdx.x >> 5;
  const int i0   = (blockIdx.x & 31) << 5;
  const int st   = blockIdx.x & 15;        // j-tile stagger
  const int lane = tid & 63, w = tid >> 6;
  const int q = tid >> 3, s = tid & 7;     // row q (0..31), col-chunk s (0..7)
  const int bN = b * NN;

  // ---- prologue: stage g, per-block shift Cb = lrelu(max f_tile + max g)
  f32x4 g4 = *(const f32x4*)(gv + bN + tid * 4);
  *(f32x4*)(gl + tid * 4) = g4;
  float gm = fmaxf(fmaxf(g4.x, g4.y), fmaxf(g4.z, g4.w));
  float fm = fv[bN + i0 + (tid & 31)];
#pragma unroll
  for (int m = 1; m < 64; m <<= 1) {
    gm = fmaxf(gm, __shfl_xor(gm, m));
    fm = fmaxf(fm, __shfl_xor(fm, m));
  }
  if (lane == 0) { red[w * 2] = gm; red[w * 2 + 1] = fm; }
  const float fr = fv[bN + i0 + q];
  __syncthreads();
  gm = fmaxf(fmaxf(red[0], red[2]), fmaxf(red[4], red[6]));
  fm = fmaxf(fmaxf(red[1], red[3]), fmaxf(red[5], red[7]));
  const float sm = fm + gm;
  const float Cb = fmaxf(sm, 0.2f * sm);   // >= max masked score; p <= 1

  const unsigned long long* maskS = maskG + ((size_t)(bN + i0 + q) << 4);
  const unsigned short*     hTS   = hT + ((size_t)(b * FD + q)) * NN + s * 8;

  float dAcc = 0.f;
  f32x4 acc[2];
  acc[0] = (f32x4){0.f, 0.f, 0.f, 0.f};
  acc[1] = (f32x4){0.f, 0.f, 0.f, 0.f};

  unsigned long long Am, Bm;
  int4 Ah0, Ah1, Bh0, Bh1;

#define TLOAD(Rm, Rh0, Rh1, jt) do { const int j0_ = (jt) << 6; \
    Rm  = maskS[jt];                                            \
    Rh0 = *(const int4*)(hTS + j0_);                            \
    Rh1 = *(const int4*)(hTS + (size_t)32 * NN + j0_); } while (0)

#define PQUAD(nib, gg, half, p) do {                                       \
    float e0 = fr + gg.x; e0 = fmaxf(e0, 0.2f * e0) - Cb;                  \
    float e1 = fr + gg.y; e1 = fmaxf(e1, 0.2f * e1) - Cb;                  \
    float e2 = fr + gg.z; e2 = fmaxf(e2, 0.2f * e2) - Cb;                  \
    float e3 = fr + gg.w; e3 = fmaxf(e3, 0.2f * e3) - Cb;                  \
    float p0 = (nib & 1u) ? __expf(e0) : 0.f;                              \
    float p1 = (nib & 2u) ? __expf(e1) : 0.f;                              \
    float p2 = (nib & 4u) ? __expf(e2) : 0.f;                              \
    float p3 = (nib & 8u) ? __expf(e3) : 0.f;                              \
    dAcc += (p0 + p1) + (p2 + p3);                                         \
    uint2 uv_;                                                             \
    uv_.x = (unsigned)f2hu(p0) | ((unsigned)f2hu(p1) << 16);               \
    uv_.y = (unsigned)f2hu(p2) | ((unsigned)f2hu(p3) << 16);               \
    *(uint2*)(Pl[p] + q * 64 +                                             \
        (((((half) << 2) + (s >> 1)) ^ (q & 7)) << 3) + ((s & 1) << 2)) = uv_; \
  } while (0)

#define MSTEP(p) do {                                                      \
    const int m16_ = lane & 15, hi_ = lane >> 4;                           \
    const int ar_ = ((w & 1) << 4) + m16_;                                 \
    const f16x8 a0_ = *(const f16x8*)(Pl[p] + ar_ * 64 + (((hi_)     ^ (ar_ & 7)) << 3)); \
    const f16x8 a1_ = *(const f16x8*)(Pl[p] + ar_ * 64 + (((hi_ + 4) ^ (ar_ & 7)) << 3)); \
    _Pragma("unroll")                                                      \
    for (int n_ = 0; n_ < 2; ++n_) {                                       \
      const int o_ = ((w >> 1) << 5) + (n_ << 4) + m16_;                   \
      const f16x8 b0_ = *(const f16x8*)(Hl[p] + o_ * 64 + (((hi_)     ^ (o_ & 7)) << 3)); \
      const f16x8 b1_ = *(const f16x8*)(Hl[p] + o_ * 64 + (((hi_ + 4) ^ (o_ & 7)) << 3)); \
      acc[n_] = __builtin_amdgcn_mfma_f32_16x16x32_f16(a0_, b0_, acc[n_], 0, 0, 0);       \
      acc[n_] = __builtin_amdgcn_mfma_f32_16x16x32_f16(a1_, b1_, acc[n_], 0, 0, 0);       \
    }                                                                      \
  } while (0)

#define TILE_ONE(t, Rm, Rh0, Rh1, p) do {                                  \
    const int jt_ = ((t) + st) & 15;                                       \
    const int jg_ = jt_ << 6;                                              \
    f32x4 g0_ = *(const f32x4*)(gl + jg_ + s * 4);                         \
    f32x4 g1_ = *(const f32x4*)(gl + jg_ + 32 + s * 4);                    \
    unsigned na_ = (unsigned)(Rm >> (s * 4)) & 0xfu;                       \
    unsigned nb_ = (unsigned)(Rm >> (32 + s * 4)) & 0xfu;                  \
    PQUAD(na_, g0_, 0, p); PQUAD(nb_, g1_, 1, p);                          \
    *(int4*)(Hl[p] + q * 64 + ((s ^ (q & 7)) << 3)) = Rh0;                 \
    *(int4*)(Hl[p] + (q + 32) * 64 + ((s ^ (q & 7)) << 3)) = Rh1;          \
    if ((t) + 2 < 16) TLOAD(Rm, Rh0, Rh1, (((t) + 2 + st) & 15));          \
    asm volatile("s_waitcnt lgkmcnt(0)" ::: "memory");                     \
    __builtin_amdgcn_s_barrier();                                          \
    MSTEP(p);                                                              \
  } while (0)

  TLOAD(Am, Ah0, Ah1, st);
  TLOAD(Bm, Bh0, Bh1, (st + 1) & 15);
#pragma unroll
  for (int t = 0; t < 16; t += 2) {
    TILE_ONE(t,     Am, Ah0, Ah1, 0);
    TILE_ONE(t + 1, Bm, Bh0, Bh1, 1);
  }
#undef TLOAD
#undef PQUAD
#undef MSTEP
#undef TILE_ONE

  // denominator: 8 threads (s=0..7) share row q
  dAcc += __shfl_xor(dAcc, 1);
  dAcc += __shfl_xor(dAcc, 2);
  dAcc += __shfl_xor(dAcc, 4);
  if (s == 0) dLds[q] = dAcc;
  __syncthreads();

  const int m16 = lane & 15, hi4 = lane >> 4;
  const int wr = (w & 1) << 4, wc = (w >> 1) << 5;
  float* outp = out + ((size_t)(bN + i0 + wr + hi4 * 4)) * FD + wc + m16;
#pragma unroll
  for (int rr = 0; rr < 4; ++rr) {
    float d   = dLds[wr + hi4 * 4 + rr];
    float inv = d > 0.f ? 1.f / d : 0.f;
#pragma unroll
    for (int n = 0; n < 2; ++n) {
      float v = acc[n][rr] * inv;
      v = v > 0.f ? v : (__expf(v) - 1.f);   // elu (alpha=1)
      outp[(size_t)rr * FD + n * 16] = v;
    }
  }
}

extern "C" void kernel_launch(void* const* d_in, const int* in_sizes, int n_in,
                              void* d_out, int out_size, void* d_ws, size_t ws_size,
                              hipStream_t stream) {
  const float* x   = (const float*)d_in[0];
  const int*   adj = (const int*)d_in[1];
  const float* W   = (const float*)d_in[2];
  const float* a   = (const float*)d_in[3];
  float* out = (float*)d_out;

  // workspace: hT fp16 [B][FD][NN] (4 MB) | fv (128 KB) | gv (128 KB) | maskG (4 MB)
  unsigned short* hT = (unsigned short*)d_ws;
  float* fv = (float*)((char*)d_ws + (size_t)BB * FD * NN * 2);
  float* gv = fv + (size_t)BB * NN;
  unsigned long long* maskG = (unsigned long long*)(gv + (size_t)BB * NN);

  gat_k01<<<dim3(512 + 2048), dim3(256), 0, stream>>>(x, W, a, adj, fv, gv, hT, maskG);
  gat_k2<<<dim3(BB * 32), dim3(256), 0, stream>>>(maskG, fv, gv, hT, out);
}

// Round 9
// 46.454 us; speedup vs baseline: 1.0206x; 1.0206x over previous
//
#include <hip/hip_runtime.h>
#include <hip/hip_bf16.h>
#include <hip/hip_fp16.h>

#define NN 1024   // nodes
#define FD 64     // feature dim (in == out)
#define BB 32     // batch

typedef __attribute__((ext_vector_type(4))) float    f32x4;
typedef __attribute__((ext_vector_type(8))) _Float16 f16x8;

static __device__ __forceinline__ unsigned short f2hu(float x) {
  _Float16 h = (_Float16)x;
  return __builtin_bit_cast(unsigned short, h);
}
static __device__ __forceinline__ f16x8 bch(int4 v) {
  return __builtin_bit_cast(f16x8, v);
}

// ---------------- Kernel 1: h = x@W (fp32), f = h@a1, g = h@a2,
// hF = h^T in MFMA B-fragment order: unit ((b*16+jt)*8 + frag)*64 + lane,
// frag = n*2+kh holds h[o = n*16+(lane&15)][j = jt*64 + kh*32 + (lane>>4)*8 + e]
__global__ __launch_bounds__(256) void gat_k1(
    const float* __restrict__ x, const float* __restrict__ W,
    const float* __restrict__ av, float* __restrict__ fv,
    float* __restrict__ gv, unsigned short* __restrict__ hF)
{
  __shared__ __align__(16) float Wl[FD * FD];
  __shared__ __align__(16) float xl[FD * 68];
  __shared__ __align__(16) unsigned short tl[FD * 64];
  __shared__ __align__(16) float al[2 * FD];

  const int tid = threadIdx.x;
  const int b   = blockIdx.x >> 4;
  const int n0  = (blockIdx.x & 15) << 6;

  if (tid < 32) ((f32x4*)al)[tid] = ((const f32x4*)av)[tid];
  {
    const int r  = tid >> 2;
    const int cb = (tid & 3) << 2;
    const f32x4* Wg = (const f32x4*)W;
    const f32x4* xg = (const f32x4*)(x + ((size_t)(b * NN + n0)) * FD);
#pragma unroll
    for (int k = 0; k < 4; ++k) {
      f32x4 wv = Wg[r * 16 + cb + k];
      f32x4 xv = xg[r * 16 + cb + k];
      *(f32x4*)(Wl + r * FD + ((cb + k) << 2)) = wv;
      *(f32x4*)(xl + r * 68 + ((cb + k) << 2)) = xv;
    }
  }
  __syncthreads();

  const int r  = tid >> 2;          // row (local j) in tile
  const int o0 = (tid & 3) << 4;    // 16 output features
  float acc[16];
#pragma unroll
  for (int i = 0; i < 16; ++i) acc[i] = 0.f;

#pragma unroll 8
  for (int f = 0; f < FD; ++f) {
    float xv = xl[r * 68 + f];
    const f32x4* wr = (const f32x4*)(Wl + f * FD + o0);
#pragma unroll
    for (int c = 0; c < 4; ++c) {
      f32x4 wv = wr[c];
      acc[c * 4 + 0] += xv * wv.x;
      acc[c * 4 + 1] += xv * wv.y;
      acc[c * 4 + 2] += xv * wv.z;
      acc[c * 4 + 3] += xv * wv.w;
    }
  }

  float fp = 0.f, gp = 0.f;
#pragma unroll
  for (int i = 0; i < 16; ++i) {
    fp += acc[i] * al[o0 + i];
    gp += acc[i] * al[FD + o0 + i];
  }
  fp += __shfl_xor(fp, 1); fp += __shfl_xor(fp, 2);
  gp += __shfl_xor(gp, 1); gp += __shfl_xor(gp, 2);
  if ((tid & 3) == 0) {
    fv[b * NN + n0 + r] = fp;
    gv[b * NN + n0 + r] = gp;
  }

#pragma unroll
  for (int i = 0; i < 16; ++i) {
    int o = o0 + i;
    tl[o * 64 + ((((r >> 3) ^ (o & 7)) << 3) | (r & 7))] = f2hu(acc[i]);
  }
  __syncthreads();
  {
    const int jt = n0 >> 6;
#pragma unroll
    for (int hh = 0; hh < 2; ++hh) {
      int u = tid + (hh << 8);
      int frag = u >> 6, l = u & 63;
      int o = ((frag >> 1) << 4) + (l & 15);
      int c = ((frag & 1) << 2) + (l >> 4);
      int4 v = *(const int4*)(tl + o * 64 + ((c ^ (o & 7)) << 3));
      *(int4*)(hF + ((((size_t)(b * 16 + jt)) * 8 + frag) * 64 + l) * 8) = v;
    }
  }
}

// ---------------- Kernel 2: masked-softmax attention + PV (MFMA f16) + elu
// 512 blocks x 4 independent waves (16 rows x full j each). Zero main-loop
// barriers. adj and hF double-buffered in registers at distance 2 with
// consume-before-reissue ordering (counted vmcnt ~16, never drains).
// REGULAR loads (no nontemporal): adj is L3-resident in the replay regime.
// Per-block j-tile stagger decorrelates blocks' instantaneous addresses.
__global__ __launch_bounds__(256, 2) void gat_k2(
    const int* __restrict__ adj, const float* __restrict__ fv,
    const float* __restrict__ gv, const unsigned short* __restrict__ hF,
    float* __restrict__ out)
{
  __shared__ __align__(16) float gl[NN];   // 4 KB
  __shared__ float red[4];

  const int tid  = threadIdx.x;
  const int b    = blockIdx.x >> 4;
  const int i0   = (blockIdx.x & 15) << 6;
  const int st   = blockIdx.x & 15;        // j-tile stagger
  const int lane = tid & 63, w = tid >> 6;
  const int m16  = lane & 15, hi = lane >> 4;
  const int bN   = b * NN;

  // ---- prologue: stage g, block shift Cb = lrelu(max f_tile + max g)
  f32x4 g4 = *(const f32x4*)(gv + bN + tid * 4);
  *(f32x4*)(gl + tid * 4) = g4;
  float gm = fmaxf(fmaxf(g4.x, g4.y), fmaxf(g4.z, g4.w));
  float fm = fv[bN + i0 + lane];
#pragma unroll
  for (int m = 1; m < 64; m <<= 1) {
    gm = fmaxf(gm, __shfl_xor(gm, m));
    fm = fmaxf(fm, __shfl_xor(fm, m));
  }
  if (lane == 0) red[w] = gm;
  const float fr = fv[bN + i0 + w * 16 + m16];
  __syncthreads();
  gm = fmaxf(fmaxf(red[0], red[1]), fmaxf(red[2], red[3]));
  const float sm = fm + gm;
  const float Cb = fmaxf(sm, 0.2f * sm);  // >= max masked score; p = exp(e-Cb) <= 1

  const int*  adjP = adj + ((size_t)(bN + i0 + w * 16 + m16)) * NN + hi * 8;
  const int4* hFb  = (const int4*)hF + (size_t)b * 8192 + lane;

  float dAcc = 0.f;
  f32x4 acc[4];
#pragma unroll
  for (int n = 0; n < 4; ++n) acc[n] = (f32x4){0.f, 0.f, 0.f, 0.f};

  int4 A0_0, A0_1, A0_2, A0_3, A1_0, A1_1, A1_2, A1_3;
  int4 H0_0, H0_1, H0_2, H0_3, H0_4, H0_5, H0_6, H0_7;
  int4 H1_0, H1_1, H1_2, H1_3, H1_4, H1_5, H1_6, H1_7;

#define LADJ(P, jt) do { const int* p_ = adjP + ((jt) << 6); \
    P##_0 = *(const int4*)(p_);                              \
    P##_1 = *(const int4*)(p_ + 4);                          \
    P##_2 = *(const int4*)(p_ + 32);                         \
    P##_3 = *(const int4*)(p_ + 36); } while (0)

#define LHF(P, jt) do { const int4* hp_ = hFb + (size_t)(jt) * 512; \
    P##_0 = hp_[0];   P##_1 = hp_[64];  P##_2 = hp_[128];           \
    P##_3 = hp_[192]; P##_4 = hp_[256]; P##_5 = hp_[320];           \
    P##_6 = hp_[384]; P##_7 = hp_[448]; } while (0)

#define PCOMP(dst, ia, ib, ga, gb) do {                                    \
    float e0 = fr + ga.x, e1 = fr + ga.y, e2 = fr + ga.z, e3 = fr + ga.w;  \
    float e4 = fr + gb.x, e5 = fr + gb.y, e6 = fr + gb.z, e7 = fr + gb.w;  \
    e0 = fmaxf(e0, 0.2f * e0) - Cb; e1 = fmaxf(e1, 0.2f * e1) - Cb;        \
    e2 = fmaxf(e2, 0.2f * e2) - Cb; e3 = fmaxf(e3, 0.2f * e3) - Cb;        \
    e4 = fmaxf(e4, 0.2f * e4) - Cb; e5 = fmaxf(e5, 0.2f * e5) - Cb;        \
    e6 = fmaxf(e6, 0.2f * e6) - Cb; e7 = fmaxf(e7, 0.2f * e7) - Cb;        \
    float p0 = (ia.x > 0) ? __expf(e0) : 0.f;                              \
    float p1 = (ia.y > 0) ? __expf(e1) : 0.f;                              \
    float p2 = (ia.z > 0) ? __expf(e2) : 0.f;                              \
    float p3 = (ia.w > 0) ? __expf(e3) : 0.f;                              \
    float p4 = (ib.x > 0) ? __expf(e4) : 0.f;                              \
    float p5 = (ib.y > 0) ? __expf(e5) : 0.f;                              \
    float p6 = (ib.z > 0) ? __expf(e6) : 0.f;                              \
    float p7 = (ib.w > 0) ? __expf(e7) : 0.f;                              \
    dAcc += ((p0 + p1) + (p2 + p3)) + ((p4 + p5) + (p6 + p7));             \
    dst = (f16x8){(_Float16)p0, (_Float16)p1, (_Float16)p2, (_Float16)p3,  \
                  (_Float16)p4, (_Float16)p5, (_Float16)p6, (_Float16)p7}; \
  } while (0)

  // STEP: consume tile t from (AP,HP); issue t+2 into same bufs AFTER the
  // consumer that frees them. MFMA's wait for HP(t) leaves A(t+1),H(t+1),
  // A(t+2) outstanding -> counted vmcnt, pipeline never drains.
#define STEP(t, AP, HP, PRE) do {                                          \
    const int jt_ = ((t) + st) & 15;                                       \
    const float* gp_ = gl + jt_ * 64 + hi * 8;                             \
    f32x4 ga0_ = *(const f32x4*)(gp_);                                     \
    f32x4 ga1_ = *(const f32x4*)(gp_ + 4);                                 \
    f32x4 gb0_ = *(const f32x4*)(gp_ + 32);                                \
    f32x4 gb1_ = *(const f32x4*)(gp_ + 36);                                \
    f16x8 pa_, pb_;                                                        \
    PCOMP(pa_, AP##_0, AP##_1, ga0_, ga1_);                                \
    PCOMP(pb_, AP##_2, AP##_3, gb0_, gb1_);                                \
    if (PRE) LADJ(AP, (((t) + 2 + st) & 15));                              \
    acc[0] = __builtin_amdgcn_mfma_f32_16x16x32_f16(pa_, bch(HP##_0), acc[0], 0, 0, 0); \
    acc[0] = __builtin_amdgcn_mfma_f32_16x16x32_f16(pb_, bch(HP##_1), acc[0], 0, 0, 0); \
    acc[1] = __builtin_amdgcn_mfma_f32_16x16x32_f16(pa_, bch(HP##_2), acc[1], 0, 0, 0); \
    acc[1] = __builtin_amdgcn_mfma_f32_16x16x32_f16(pb_, bch(HP##_3), acc[1], 0, 0, 0); \
    acc[2] = __builtin_amdgcn_mfma_f32_16x16x32_f16(pa_, bch(HP##_4), acc[2], 0, 0, 0); \
    acc[2] = __builtin_amdgcn_mfma_f32_16x16x32_f16(pb_, bch(HP##_5), acc[2], 0, 0, 0); \
    acc[3] = __builtin_amdgcn_mfma_f32_16x16x32_f16(pa_, bch(HP##_6), acc[3], 0, 0, 0); \
    acc[3] = __builtin_amdgcn_mfma_f32_16x16x32_f16(pb_, bch(HP##_7), acc[3], 0, 0, 0); \
    if (PRE) LHF(HP, (((t) + 2 + st) & 15));                               \
  } while (0)

  LADJ(A0, st);            LHF(H0, st);
  LADJ(A1, (st + 1) & 15); LHF(H1, (st + 1) & 15);

  STEP(0,  A0, H0, 1); STEP(1,  A1, H1, 1);
  STEP(2,  A0, H0, 1); STEP(3,  A1, H1, 1);
  STEP(4,  A0, H0, 1); STEP(5,  A1, H1, 1);
  STEP(6,  A0, H0, 1); STEP(7,  A1, H1, 1);
  STEP(8,  A0, H0, 1); STEP(9,  A1, H1, 1);
  STEP(10, A0, H0, 1); STEP(11, A1, H1, 1);
  STEP(12, A0, H0, 1); STEP(13, A1, H1, 1);
  STEP(14, A0, H0, 0); STEP(15, A1, H1, 0);

#undef LADJ
#undef LHF
#undef PCOMP
#undef STEP

  // denominator: combine the 4 hi-groups sharing each row (no LDS, no barrier)
  dAcc += __shfl_xor(dAcc, 16);
  dAcc += __shfl_xor(dAcc, 32);

  float* outB = out + ((size_t)(bN + i0 + w * 16)) * FD;
#pragma unroll
  for (int rr = 0; rr < 4; ++rr) {
    const int lr = hi * 4 + rr;           // local row (C/D layout)
    float d   = __shfl(dAcc, lr);
    float inv = d > 0.f ? 1.f / d : 0.f;
#pragma unroll
    for (int n = 0; n < 4; ++n) {
      float v = acc[n][rr] * inv;
      v = v > 0.f ? v : (__expf(v) - 1.f);  // elu (alpha=1)
      outB[(size_t)lr * FD + n * 16 + m16] = v;
    }
  }
}

extern "C" void kernel_launch(void* const* d_in, const int* in_sizes, int n_in,
                              void* d_out, int out_size, void* d_ws, size_t ws_size,
                              hipStream_t stream) {
  const float* x   = (const float*)d_in[0];
  const int*   adj = (const int*)d_in[1];
  const float* W   = (const float*)d_in[2];
  const float* a   = (const float*)d_in[3];
  float* out = (float*)d_out;

  // workspace: hF fp16 fragment-ordered (4 MB) | fv (128 KB) | gv (128 KB)
  unsigned short* hF = (unsigned short*)d_ws;
  float* fv = (float*)((char*)d_ws + (size_t)BB * FD * NN * 2);
  float* gv = fv + (size_t)BB * NN;

  gat_k1<<<dim3(BB * 16), dim3(256), 0, stream>>>(x, W, a, fv, gv, hF);
  gat_k2<<<dim3(BB * 16), dim3(256), 0, stream>>>(adj, fv, gv, hF, out);
}